// Round 1
// 60.450 us; speedup vs baseline: 1.0223x; 1.0223x over previous
//
#include <hip/hip_runtime.h>
#include <math.h>

// Exact replay of: y = 0; repeat 1e6: y = f32_rne(y + eps)   (sequential f32)
// plus x_double = f32(1e6 * (double)eps), out = |x_double - y|.
//
// Fast-forward trick: within one f32 binade, RNE(y + c) advances the bit
// pattern by a CONSTANT integer stride s (ties-to-even settles after one
// step; unsettled-tie parity fails the equal-stride guard). Take 2 real FP
// steps, verify 3 consecutive points share a binade with equal bit strides,
// then jump k*s in bit space (k capped to stay strictly inside the binade
// and within the remaining step budget). Binade crossings / tie-settling are
// handled by real FP adds. O(~50) iterations total.
//
// R1 change: all bit-space arithmetic in uint32 (patterns < 2^31, strides &
// spans < 2^23, rem <= 1e6). The old 64-bit integer divide (software
// sequence, ~100s of dependent cycles per loop iteration on a single lane)
// is replaced by an EXACT f32 divide + <=2-step fixup: n, s < 2^24 are both
// exactly representable in f32, so floor(n/s) is recovered exactly.
__global__ __launch_bounds__(64, 1) void eps_accum_kernel(
        const float* __restrict__ eps_p, float* __restrict__ out) {
    if (threadIdx.x != 0 || blockIdx.x != 0) return;

    const float c = eps_p[0];
    int rem = 1000000;
    float y = 0.0f;

    while (rem > 0) {
        float y1 = y + c;
        if (y1 == y) break;                  // fixed point: rest are no-ops
        if (rem == 1) { y = y1; break; }     // last step
        float y2 = y1 + c;
        if (y2 == y1) { y = y1; break; }     // fixed after consuming 1 step

        unsigned int u0 = __float_as_uint(y);
        unsigned int u1 = __float_as_uint(y1);
        unsigned int u2 = __float_as_uint(y2);

        // Jump valid only if y, y1, y2 share a binade and the two observed
        // bit strides match (rejects unsettled ties-to-even parity).
        // Positive floats: bit patterns are monotone in value.
        if (u2 > u1 && (u1 - u0) == (u2 - u1) && (u0 >> 23) == (u2 >> 23)) {
            unsigned int s   = u2 - u1;                    // 1 .. 2^23-1
            unsigned int top = ((u2 >> 23) + 1) << 23;     // next-binade pattern
            unsigned int n   = (top - 1) - u1;             // head-room, < 2^23

            // k = floor(n / s), exact: f32 divide + bounded fixup.
            unsigned int k = (unsigned int)__fdividef((float)n, (float)s);
            while (k * s > n) --k;                         // k*s <= n+s < 2^24
            while ((k + 1) * s <= n) ++k;

            unsigned int krem = (unsigned int)(rem - 1);
            if (k > krem) k = krem;
            if (k >= 1) {
                y = __uint_as_float(u1 + k * s);           // stays < top
                rem -= (int)(1 + k);
                continue;
            }
        }
        // Fallback: consume both real FP steps (guarantees progress).
        y = y2;
        rem -= 2;
    }

    // x-path: reference accumulates the python double 0.001; we only have
    // f32 eps. 1e6 * (double)eps then cast to f32 differs from the reference
    // value (1000.0f) by one f32 ulp at 1000 (6.1e-5) -- far under the
    // absmax threshold. Serial double accumulation would change nothing at
    // f32 precision vs the multiply.
    float xd = (float)(1000000.0 * (double)c);
    out[0] = fabsf(xd - y);
}

extern "C" void kernel_launch(void* const* d_in, const int* in_sizes, int n_in,
                              void* d_out, int out_size, void* d_ws, size_t ws_size,
                              hipStream_t stream) {
    // inputs: d_in[0] = x (1024*1024 f32, ignored), d_in[1] = eps (1 f32).
    // Pick the size-1 input defensively.
    int eps_idx = 1;
    for (int i = 0; i < n_in; ++i) {
        if (in_sizes[i] == 1) { eps_idx = i; break; }
    }
    const float* eps = (const float*)d_in[eps_idx];
    float* out = (float*)d_out;
    eps_accum_kernel<<<1, 64, 0, stream>>>(eps, out);
}